// Round 1
// baseline (10783.415 us; speedup 1.0000x reference)
//
#include <hip/hip_runtime.h>

// LSTM  B=64 T=512 D=256 H=512, fp32 in/out.
// Persistent kernel: 4 clusters x 32 WGs, 16 batches/cluster, 16 h-cols/WG.
// Weights bf16(RNE) resident in LDS in MFMA B-frag order; z=[x|h] split into
// bf16 hi/lo planes (2-term compensated MFMA). Per-step cluster sync via
// per-WG monotonic flags (release/acquire, agent scope), ping-pong h buffers.

#define B_   64
#define T_   512
#define D_   256
#define H_   512
#define KTOT 768          // D_+H_
#define NCL  4            // clusters
#define WPC  32           // workgroups per cluster
#define BPC  16           // batches per cluster
#define NKT  24           // K tiles of 32
#define NCT  4            // col tiles of 16 (64 gemm cols = 16 hc x 4 gates)
#define ZPAD 776          // padded z row length in ushorts (1552B: 16B-aligned, 4-bank row stride)

typedef __attribute__((ext_vector_type(8)))  short  short8;
typedef __attribute__((ext_vector_type(4)))  float  f32x4;
typedef __attribute__((ext_vector_type(4)))  float  float4_;
typedef unsigned short ushort_t;
typedef unsigned int   uint_t;

__device__ __forceinline__ ushort_t f2bf(float f) {           // RNE f32->bf16
    unsigned int u = __float_as_uint(f);
    u += 0x7FFFu + ((u >> 16) & 1u);
    return (ushort_t)(u >> 16);
}
__device__ __forceinline__ float bf2f(ushort_t h) {
    return __uint_as_float(((unsigned int)h) << 16);
}
__device__ __forceinline__ float sigm_(float x) { return 1.0f / (1.0f + __expf(-x)); }
__device__ __forceinline__ float tanh_(float x) {
    float a = fabsf(x);
    float e = __expf(-2.0f * a);
    float r = (1.0f - e) / (1.0f + e);
    return copysignf(r, x);
}

__global__ __launch_bounds__(256, 1)
void lstm_persistent(const float* __restrict__ x,
                     const float* __restrict__ Wf, const float* __restrict__ bf_,
                     const float* __restrict__ Wi, const float* __restrict__ bi_,
                     const float* __restrict__ Wo, const float* __restrict__ bo_,
                     const float* __restrict__ Wc, const float* __restrict__ bc_,
                     float* __restrict__ out,
                     uint_t* __restrict__ flags,
                     ushort_t* __restrict__ hhi, ushort_t* __restrict__ hlo)
{
    // LDS: W frag-major 96KB + z_hi/z_lo planes + bias. partial-C aliases z_hi.
    __shared__ ushort_t w_lds[NCT * NKT * 512];   // 98304 B
    __shared__ ushort_t z_hi[16 * ZPAD];          // 24832 B
    __shared__ ushort_t z_lo[16 * ZPAD];          // 24832 B
    __shared__ float    bias_lds[64];             //   256 B

    const int tid  = threadIdx.x;
    const int lane = tid & 63;
    const int wv   = tid >> 6;          // wave 0..3
    const int cl   = blockIdx.x >> 5;   // cluster 0..3
    const int w    = blockIdx.x & 31;   // wg-in-cluster 0..31
    const int b0   = cl * BPC;          // first batch
    const int hc0  = w * 16;            // first h-col (global)

    // ---- one-time: repack W slice (fp32 global -> bf16 LDS, B-frag order) ----
    // frag: lane l holds B[k = kt*32 + (l>>4)*8 + j][n = ct*16 + (l&15)], j=0..7
    for (int idx = tid; idx < NCT * NKT * 64; idx += 256) {
        int blk   = idx >> 6;           // 0..95
        int ln    = idx & 63;
        int ct    = blk / NKT;
        int kt    = blk % NKT;
        int col16 = ln & 15;
        int kc    = ln >> 4;
        int j     = ct * 16 + col16;    // gemm col 0..63  (j = hc*4 + g)
        int hc    = j >> 2, g = j & 3;
        int gcol  = hc0 + hc;
        const float* Wsrc = (g == 0) ? Wf : ((g == 1) ? Wi : ((g == 2) ? Wo : Wc));
        int krow0 = kt * 32 + kc * 8;
        short8 v;
#pragma unroll
        for (int jj = 0; jj < 8; ++jj)
            v[jj] = (short)f2bf(Wsrc[(size_t)(krow0 + jj) * H_ + gcol]);
        *(short8*)(w_lds + blk * 512 + ln * 8) = v;
    }
    if (tid < 64) {
        int g = tid & 3, hc = tid >> 2;
        const float* bsrc = (g == 0) ? bf_ : ((g == 1) ? bi_ : ((g == 2) ? bo_ : bc_));
        bias_lds[tid] = bsrc[hc0 + hc];
    }
    __syncthreads();

    // ---- persistent state ----
    float c_reg = 0.0f;                 // cell state for (batch=tid>>4, hc=tid&15)
    const int bx = tid & 15, ch = tid >> 4;   // z-build mapping
    const float* xbase = x + (size_t)(b0 + bx) * (T_ * D_) + ch * 16;

    // prefetch x for t=0
    float4_ xr0, xr1, xr2, xr3;
    {
        const float4_* p = (const float4_*)xbase;
        xr0 = p[0]; xr1 = p[1]; xr2 = p[2]; xr3 = p[3];
    }

    const int l15 = lane & 15, lk = lane >> 4;
    const ushort_t* zh_frag = z_hi + l15 * ZPAD + lk * 8;
    const ushort_t* zl_frag = z_lo + l15 * ZPAD + lk * 8;
    const ushort_t* wfrag   = w_lds + lane * 8;
    float* pC = (float*)z_hi;           // 16KB partial-C buffer aliased on z_hi

    for (int t = 0; t < T_; ++t) {
        // ---- wait for h(t) from all WGs of this cluster ----
        if (t > 0 && lane < WPC) {
            const uint_t* fl = flags + cl * WPC + lane;
            while (__hip_atomic_load(fl, __ATOMIC_ACQUIRE, __HIP_MEMORY_SCOPE_AGENT) < (uint_t)t)
                __builtin_amdgcn_s_sleep(1);
        }

        // ---- build z planes: x part from prefetched regs ----
        {
            ushort_t hp[16], lp[16];
#pragma unroll
            for (int e = 0; e < 4; ++e) {
                float xf; ushort_t hb;
                xf = xr0[e]; hb = f2bf(xf); hp[e]      = hb; lp[e]      = f2bf(xf - bf2f(hb));
                xf = xr1[e]; hb = f2bf(xf); hp[4 + e]  = hb; lp[4 + e]  = f2bf(xf - bf2f(hb));
                xf = xr2[e]; hb = f2bf(xf); hp[8 + e]  = hb; lp[8 + e]  = f2bf(xf - bf2f(hb));
                xf = xr3[e]; hb = f2bf(xf); hp[12 + e] = hb; lp[12 + e] = f2bf(xf - bf2f(hb));
            }
            short8 a0, a1, b0v, b1v;
#pragma unroll
            for (int e = 0; e < 8; ++e) {
                a0[e] = (short)hp[e]; a1[e] = (short)hp[8 + e];
                b0v[e] = (short)lp[e]; b1v[e] = (short)lp[8 + e];
            }
            ushort_t* zh = z_hi + bx * ZPAD + ch * 16;
            ushort_t* zl = z_lo + bx * ZPAD + ch * 16;
            ((short8*)zh)[0] = a0; ((short8*)zh)[1] = a1;
            ((short8*)zl)[0] = b0v; ((short8*)zl)[1] = b1v;
        }
        // ---- h part: copy cluster h(t) (hi/lo planes) from global ----
        {
            size_t base = ((size_t)((t & 1) * NCL + cl) * BPC + bx) * H_ + ch * 32;
            ushort_t* dh = z_hi + bx * ZPAD + 256 + ch * 32;
            ushort_t* dl = z_lo + bx * ZPAD + 256 + ch * 32;
#pragma unroll
            for (int q = 0; q < 4; ++q) {
                *(short8*)(dh + q * 8) = *(const short8*)(hhi + base + q * 8);
                *(short8*)(dl + q * 8) = *(const short8*)(hlo + base + q * 8);
            }
        }
        __syncthreads();

        // ---- MFMA: waves split K (6 kt each), all 4 col-tiles ----
        f32x4 acc0 = {0.f, 0.f, 0.f, 0.f};
        f32x4 acc1 = {0.f, 0.f, 0.f, 0.f};
        f32x4 acc2 = {0.f, 0.f, 0.f, 0.f};
        f32x4 acc3 = {0.f, 0.f, 0.f, 0.f};
        const int kt0 = wv * 6;
#pragma unroll
        for (int k6 = 0; k6 < 6; ++k6) {
            const int kt = kt0 + k6;
            short8 ah = *(const short8*)(zh_frag + kt * 32);
            short8 al = *(const short8*)(zl_frag + kt * 32);
            short8 bb;
            bb = *(const short8*)(wfrag + (0 * NKT + kt) * 512);
            acc0 = __builtin_amdgcn_mfma_f32_16x16x32_bf16(ah, bb, acc0, 0, 0, 0);
            acc0 = __builtin_amdgcn_mfma_f32_16x16x32_bf16(al, bb, acc0, 0, 0, 0);
            bb = *(const short8*)(wfrag + (1 * NKT + kt) * 512);
            acc1 = __builtin_amdgcn_mfma_f32_16x16x32_bf16(ah, bb, acc1, 0, 0, 0);
            acc1 = __builtin_amdgcn_mfma_f32_16x16x32_bf16(al, bb, acc1, 0, 0, 0);
            bb = *(const short8*)(wfrag + (2 * NKT + kt) * 512);
            acc2 = __builtin_amdgcn_mfma_f32_16x16x32_bf16(ah, bb, acc2, 0, 0, 0);
            acc2 = __builtin_amdgcn_mfma_f32_16x16x32_bf16(al, bb, acc2, 0, 0, 0);
            bb = *(const short8*)(wfrag + (3 * NKT + kt) * 512);
            acc3 = __builtin_amdgcn_mfma_f32_16x16x32_bf16(ah, bb, acc3, 0, 0, 0);
            acc3 = __builtin_amdgcn_mfma_f32_16x16x32_bf16(al, bb, acc3, 0, 0, 0);
        }
        __syncthreads();   // z_hi reads done; safe to overwrite with partial C

        // ---- write per-wave partial C (C layout: col=lane&15, row=(lane>>4)*4+i) ----
#pragma unroll
        for (int i = 0; i < 4; ++i) {
            int r = (lk * 4 + i) * 16 + l15;
            pC[(wv * 4 + 0) * 256 + r] = acc0[i];
            pC[(wv * 4 + 1) * 256 + r] = acc1[i];
            pC[(wv * 4 + 2) * 256 + r] = acc2[i];
            pC[(wv * 4 + 3) * 256 + r] = acc3[i];
        }
        __syncthreads();

        // ---- gates + state update: thread -> (batch=tid>>4, hc=tid&15) ----
        {
            const int gb = tid >> 4, ghc = tid & 15;
            const int ctg = ghc >> 2;
            float pre[4];
#pragma unroll
            for (int g = 0; g < 4; ++g) {
                float s = bias_lds[ghc * 4 + g];
                const int col = (ghc & 3) * 4 + g;
#pragma unroll
                for (int wv2 = 0; wv2 < 4; ++wv2)
                    s += pC[(wv2 * 4 + ctg) * 256 + gb * 16 + col];
                pre[g] = s;
            }
            float fg = sigm_(pre[0]);
            float ig = sigm_(pre[1]);
            float og = sigm_(pre[2]);
            float cc = tanh_(pre[3]);
            c_reg = fmaf(c_reg, fg, cc * ig);
            float hv = og * tanh_(c_reg);

            out[((size_t)(b0 + gb) * T_ + t) * H_ + hc0 + ghc] = hv;

            ushort_t hb = f2bf(hv);
            ushort_t lb = f2bf(hv - bf2f(hb));
            size_t ho = ((size_t)(((t + 1) & 1) * NCL + cl) * BPC + gb) * H_ + hc0 + ghc;
            hhi[ho] = hb;
            hlo[ho] = lb;
        }
        __threadfence();     // make h(t+1) device-visible
        __syncthreads();     // all threads' stores fenced before flag
        if (tid == 0)
            __hip_atomic_store(flags + cl * WPC + w, (uint_t)(t + 1),
                               __ATOMIC_RELEASE, __HIP_MEMORY_SCOPE_AGENT);

        // ---- prefetch x for t+1 (overlaps with other WGs' work / next poll) ----
        if (t + 1 < T_) {
            const float4_* p = (const float4_*)(xbase + (size_t)(t + 1) * D_);
            xr0 = p[0]; xr1 = p[1]; xr2 = p[2]; xr3 = p[3];
        }
    }
}

extern "C" void kernel_launch(void* const* d_in, const int* in_sizes, int n_in,
                              void* d_out, int out_size, void* d_ws, size_t ws_size,
                              hipStream_t stream) {
    const float* x  = (const float*)d_in[0];
    const float* Wf = (const float*)d_in[1];
    const float* bf = (const float*)d_in[2];
    const float* Wi = (const float*)d_in[3];
    const float* bi = (const float*)d_in[4];
    const float* Wo = (const float*)d_in[5];
    const float* bo = (const float*)d_in[6];
    const float* Wc = (const float*)d_in[7];
    const float* bc = (const float*)d_in[8];
    float* out = (float*)d_out;

    // workspace layout: [0,512) flags (4 clusters x 32 u32, 128B/cluster)
    //                   [512, 512+131072) h hi planes [2][4][16][512] u16
    //                   [+131072)         h lo planes
    uint_t*   flags = (uint_t*)d_ws;
    ushort_t* hhi   = (ushort_t*)((char*)d_ws + 512);
    ushort_t* hlo   = (ushort_t*)((char*)d_ws + 512 + 131072);

    hipMemsetAsync(d_ws, 0, 512 + 2 * 131072, stream);  // zero flags + h(0)

    lstm_persistent<<<dim3(NCL * WPC), dim3(256), 0, stream>>>(
        x, Wf, bf, Wi, bi, Wo, bo, Wc, bc, out, flags, hhi, hlo);
}

// Round 2
// 1687.442 us; speedup vs baseline: 6.3904x; 6.3904x over previous
//
#include <hip/hip_runtime.h>

// LSTM  B=64 T=512 D=256 H=512, fp32 in/out.
// Persistent kernel: 4 clusters x 32 WGs, 16 batches/cluster, 16 h-cols/WG.
// Weights bf16(RNE) resident in LDS in MFMA B-frag order; z=[x|h] split into
// bf16 hi/lo planes (2-term compensated MFMA).
// R2: cross-WG comms via RELAXED agent-scope atomics only (global_load/store
// sc1, coherent at memory-side L3, NO buffer_inv/buffer_wbl2). h hi/lo packed
// into one u32; coalesced 32-dword gather issued into regs before LDS unpack.

#define B_   64
#define T_   512
#define D_   256
#define H_   512
#define NCL  4            // clusters
#define WPC  32           // workgroups per cluster
#define BPC  16           // batches per cluster
#define NKT  24           // K tiles of 32
#define NCT  4            // col tiles of 16 (64 gemm cols = 16 hc x 4 gates)
#define ZPAD 776          // padded z row length in ushorts

typedef __attribute__((ext_vector_type(8)))  short  short8;
typedef __attribute__((ext_vector_type(4)))  float  f32x4;
typedef __attribute__((ext_vector_type(4)))  float  float4_;
typedef unsigned short ushort_t;
typedef unsigned int   uint_t;

__device__ __forceinline__ ushort_t f2bf(float f) {           // RNE f32->bf16
    unsigned int u = __float_as_uint(f);
    u += 0x7FFFu + ((u >> 16) & 1u);
    return (ushort_t)(u >> 16);
}
__device__ __forceinline__ float bf2f(ushort_t h) {
    return __uint_as_float(((unsigned int)h) << 16);
}
__device__ __forceinline__ float sigm_(float x) { return 1.0f / (1.0f + __expf(-x)); }
__device__ __forceinline__ float tanh_(float x) {
    float a = fabsf(x);
    float e = __expf(-2.0f * a);
    float r = (1.0f - e) / (1.0f + e);
    return copysignf(r, x);
}

__global__ __launch_bounds__(256, 1)
void lstm_persistent(const float* __restrict__ x,
                     const float* __restrict__ Wf, const float* __restrict__ bf_,
                     const float* __restrict__ Wi, const float* __restrict__ bi_,
                     const float* __restrict__ Wo, const float* __restrict__ bo_,
                     const float* __restrict__ Wc, const float* __restrict__ bc_,
                     float* __restrict__ out,
                     uint_t* __restrict__ flags,
                     uint_t* __restrict__ hpack)   // [2][NCL][BPC][H_] u32 (hi<<16|lo)
{
    __shared__ ushort_t w_lds[NCT * NKT * 512];   // 98304 B
    __shared__ ushort_t z_hi[16 * ZPAD];          // 24832 B
    __shared__ ushort_t z_lo[16 * ZPAD];          // 24832 B
    __shared__ float    bias_lds[64];             //   256 B

    const int tid  = threadIdx.x;
    const int lane = tid & 63;
    const int wv   = tid >> 6;          // wave 0..3
    const int cl   = blockIdx.x >> 5;   // cluster 0..3
    const int w    = blockIdx.x & 31;   // wg-in-cluster 0..31
    const int b0   = cl * BPC;          // first batch
    const int hc0  = w * 16;            // first h-col (global)

    // ---- one-time: repack W slice (fp32 global -> bf16 LDS, B-frag order) ----
    // frag: lane l holds B[k = kt*32 + (l>>4)*8 + j][n = ct*16 + (l&15)], j=0..7
    for (int idx = tid; idx < NCT * NKT * 64; idx += 256) {
        int blk   = idx >> 6;           // 0..95
        int ln    = idx & 63;
        int ct    = blk / NKT;
        int kt    = blk % NKT;
        int col16 = ln & 15;
        int kc    = ln >> 4;
        int j     = ct * 16 + col16;    // gemm col 0..63  (j = hc*4 + g)
        int hc    = j >> 2, g = j & 3;
        int gcol  = hc0 + hc;
        const float* Wsrc = (g == 0) ? Wf : ((g == 1) ? Wi : ((g == 2) ? Wo : Wc));
        int krow0 = kt * 32 + kc * 8;
        short8 v;
#pragma unroll
        for (int jj = 0; jj < 8; ++jj)
            v[jj] = (short)f2bf(Wsrc[(size_t)(krow0 + jj) * H_ + gcol]);
        *(short8*)(w_lds + blk * 512 + ln * 8) = v;
    }
    if (tid < 64) {
        int g = tid & 3, hc = tid >> 2;
        const float* bsrc = (g == 0) ? bf_ : ((g == 1) ? bi_ : ((g == 2) ? bo_ : bc_));
        bias_lds[tid] = bsrc[hc0 + hc];
    }
    __syncthreads();

    // ---- persistent state ----
    float c_reg = 0.0f;                 // cell state for (batch=tid>>4, hc=tid&15)
    const int bx = tid & 15, ch = tid >> 4;   // z-build mapping
    const float* xbase = x + (size_t)(b0 + bx) * (T_ * D_) + ch * 16;

    // prefetch x for t=0
    float4_ xr0, xr1, xr2, xr3;
    {
        const float4_* p = (const float4_*)xbase;
        xr0 = p[0]; xr1 = p[1]; xr2 = p[2]; xr3 = p[3];
    }

    const int l15 = lane & 15, lk = lane >> 4;
    const ushort_t* zh_frag = z_hi + l15 * ZPAD + lk * 8;
    const ushort_t* zl_frag = z_lo + l15 * ZPAD + lk * 8;
    const ushort_t* wfrag   = w_lds + lane * 8;
    float* pC = (float*)z_hi;           // 16KB partial-C buffer aliased on z_hi

    const int gb = tid >> 4, ghc = tid & 15;   // gates mapping
    const int ctg = ghc >> 2;

    for (int t = 0; t < T_; ++t) {
        // ---- (a) build z x-part from prefetched regs (independent of h) ----
        {
            ushort_t hp[16], lp[16];
#pragma unroll
            for (int e = 0; e < 4; ++e) {
                float xf; ushort_t hb;
                xf = xr0[e]; hb = f2bf(xf); hp[e]      = hb; lp[e]      = f2bf(xf - bf2f(hb));
                xf = xr1[e]; hb = f2bf(xf); hp[4 + e]  = hb; lp[4 + e]  = f2bf(xf - bf2f(hb));
                xf = xr2[e]; hb = f2bf(xf); hp[8 + e]  = hb; lp[8 + e]  = f2bf(xf - bf2f(hb));
                xf = xr3[e]; hb = f2bf(xf); hp[12 + e] = hb; lp[12 + e] = f2bf(xf - bf2f(hb));
            }
            short8 a0, a1, b0v, b1v;
#pragma unroll
            for (int e = 0; e < 8; ++e) {
                a0[e] = (short)hp[e]; a1[e] = (short)hp[8 + e];
                b0v[e] = (short)lp[e]; b1v[e] = (short)lp[8 + e];
            }
            ushort_t* zh = z_hi + bx * ZPAD + ch * 16;
            ushort_t* zl = z_lo + bx * ZPAD + ch * 16;
            ((short8*)zh)[0] = a0; ((short8*)zh)[1] = a1;
            ((short8*)zl)[0] = b0v; ((short8*)zl)[1] = b1v;
        }

        // ---- (b) wait for h(t): relaxed polls (plain sc1 loads, no L2 inval) ----
        if (t > 0) {
            if (lane < WPC) {
                const uint_t* fl = flags + cl * WPC + lane;
                while (__hip_atomic_load(fl, __ATOMIC_RELAXED, __HIP_MEMORY_SCOPE_AGENT) < (uint_t)t)
                    __builtin_amdgcn_s_sleep(2);
            }
            __builtin_amdgcn_fence(__ATOMIC_ACQUIRE, "workgroup");  // waitcnt-only fence
        }

        // ---- (c) gather cluster h(t): 32 coalesced relaxed dword loads -> regs ----
        {
            const uint_t* hsrc = hpack + (size_t)((t & 1) * NCL + cl) * (BPC * H_);
            uint_t hvr[32];
#pragma unroll
            for (int q = 0; q < 32; ++q)
                hvr[q] = __hip_atomic_load(hsrc + q * 256 + tid,
                                           __ATOMIC_RELAXED, __HIP_MEMORY_SCOPE_AGENT);
#pragma unroll
            for (int q = 0; q < 32; ++q) {
                int zo = (q >> 1) * ZPAD + 256 + (q & 1) * 256 + tid;
                z_hi[zo] = (ushort_t)(hvr[q] >> 16);
                z_lo[zo] = (ushort_t)(hvr[q] & 0xffffu);
            }
        }
        __syncthreads();

        // ---- prefetch x for t+1 (latency hides under MFMA+gates) ----
        if (t + 1 < T_) {
            const float4_* p = (const float4_*)(xbase + (size_t)(t + 1) * D_);
            xr0 = p[0]; xr1 = p[1]; xr2 = p[2]; xr3 = p[3];
        }

        // ---- (e) MFMA: waves split K (6 kt each), all 4 col-tiles ----
        f32x4 acc0 = {0.f, 0.f, 0.f, 0.f};
        f32x4 acc1 = {0.f, 0.f, 0.f, 0.f};
        f32x4 acc2 = {0.f, 0.f, 0.f, 0.f};
        f32x4 acc3 = {0.f, 0.f, 0.f, 0.f};
        const int kt0 = wv * 6;
#pragma unroll
        for (int k6 = 0; k6 < 6; ++k6) {
            const int kt = kt0 + k6;
            short8 ah = *(const short8*)(zh_frag + kt * 32);
            short8 al = *(const short8*)(zl_frag + kt * 32);
            short8 bb;
            bb = *(const short8*)(wfrag + (0 * NKT + kt) * 512);
            acc0 = __builtin_amdgcn_mfma_f32_16x16x32_bf16(ah, bb, acc0, 0, 0, 0);
            acc0 = __builtin_amdgcn_mfma_f32_16x16x32_bf16(al, bb, acc0, 0, 0, 0);
            bb = *(const short8*)(wfrag + (1 * NKT + kt) * 512);
            acc1 = __builtin_amdgcn_mfma_f32_16x16x32_bf16(ah, bb, acc1, 0, 0, 0);
            acc1 = __builtin_amdgcn_mfma_f32_16x16x32_bf16(al, bb, acc1, 0, 0, 0);
            bb = *(const short8*)(wfrag + (2 * NKT + kt) * 512);
            acc2 = __builtin_amdgcn_mfma_f32_16x16x32_bf16(ah, bb, acc2, 0, 0, 0);
            acc2 = __builtin_amdgcn_mfma_f32_16x16x32_bf16(al, bb, acc2, 0, 0, 0);
            bb = *(const short8*)(wfrag + (3 * NKT + kt) * 512);
            acc3 = __builtin_amdgcn_mfma_f32_16x16x32_bf16(ah, bb, acc3, 0, 0, 0);
            acc3 = __builtin_amdgcn_mfma_f32_16x16x32_bf16(al, bb, acc3, 0, 0, 0);
        }
        __syncthreads();   // z reads done; safe to overwrite z_hi with partial C

        // ---- write per-wave partial C (C layout: col=lane&15, row=(lane>>4)*4+i) ----
#pragma unroll
        for (int i = 0; i < 4; ++i) {
            int r = (lk * 4 + i) * 16 + l15;
            pC[(wv * 4 + 0) * 256 + r] = acc0[i];
            pC[(wv * 4 + 1) * 256 + r] = acc1[i];
            pC[(wv * 4 + 2) * 256 + r] = acc2[i];
            pC[(wv * 4 + 3) * 256 + r] = acc3[i];
        }
        __syncthreads();

        // ---- gates + state update: thread -> (batch=gb, hc=ghc) ----
        float hout;
        {
            float pre[4];
#pragma unroll
            for (int g = 0; g < 4; ++g) {
                float s = bias_lds[ghc * 4 + g];
                const int col = (ghc & 3) * 4 + g;
#pragma unroll
                for (int wv2 = 0; wv2 < 4; ++wv2)
                    s += pC[(wv2 * 4 + ctg) * 256 + gb * 16 + col];
                pre[g] = s;
            }
            float fg = sigm_(pre[0]);
            float ig = sigm_(pre[1]);
            float og = sigm_(pre[2]);
            float cc = tanh_(pre[3]);
            c_reg = fmaf(c_reg, fg, cc * ig);
            hout = og * tanh_(c_reg);

            uint_t hb = (uint_t)f2bf(hout);
            uint_t lb = (uint_t)f2bf(hout - bf2f((ushort_t)hb));
            size_t ho = (size_t)(((t + 1) & 1) * NCL + cl) * (BPC * H_)
                      + (size_t)gb * H_ + hc0 + ghc;
            __hip_atomic_store(hpack + ho, (hb << 16) | lb,
                               __ATOMIC_RELAXED, __HIP_MEMORY_SCOPE_AGENT);
        }

        // sc1 store ack = coherence-point arrival; barrier drains vmcnt(0)
        asm volatile("s_waitcnt vmcnt(0)" ::: "memory");
        __syncthreads();

        if (tid == 0)
            __hip_atomic_store(flags + cl * WPC + w, (uint_t)(t + 1),
                               __ATOMIC_RELAXED, __HIP_MEMORY_SCOPE_AGENT);

        // ---- deferred out store (not on the critical sync path) ----
        out[((size_t)(b0 + gb) * T_ + t) * H_ + hc0 + ghc] = hout;
    }
}

extern "C" void kernel_launch(void* const* d_in, const int* in_sizes, int n_in,
                              void* d_out, int out_size, void* d_ws, size_t ws_size,
                              hipStream_t stream) {
    const float* x  = (const float*)d_in[0];
    const float* Wf = (const float*)d_in[1];
    const float* bf = (const float*)d_in[2];
    const float* Wi = (const float*)d_in[3];
    const float* bi = (const float*)d_in[4];
    const float* Wo = (const float*)d_in[5];
    const float* bo = (const float*)d_in[6];
    const float* Wc = (const float*)d_in[7];
    const float* bc = (const float*)d_in[8];
    float* out = (float*)d_out;

    // workspace: [0,512)    flags (4 clusters x 32 u32)
    //            [1024, +262144) hpack [2][4][16][512] u32 (hi<<16|lo)
    uint_t* flags = (uint_t*)d_ws;
    uint_t* hpack = (uint_t*)((char*)d_ws + 1024);

    hipMemsetAsync(d_ws, 0, 1024 + 2 * NCL * BPC * H_ * sizeof(uint_t), stream);

    lstm_persistent<<<dim3(NCL * WPC), dim3(256), 0, stream>>>(
        x, Wf, bf, Wi, bi, Wo, bo, Wc, bc, out, flags, hpack);
}